// Round 5
// baseline (529.820 us; speedup 1.0000x reference)
//
#include <hip/hip_runtime.h>

#define NFOLDS 12
#define EPS 1e-8f
#define BATCH 2048
#define IN_DIM 128
#define UNITS 256
#define RB 4
#define LOG2E 1.44269504088896340736f
#define VCLAMP 4.5f

#if __has_builtin(__builtin_amdgcn_rcpf)
#define RCPF(x) __builtin_amdgcn_rcpf(x)
#else
#define RCPF(x) (1.0f / (x))
#endif

typedef float f2 __attribute__((ext_vector_type(2)));
typedef float f4 __attribute__((ext_vector_type(4)));
typedef unsigned int u2 __attribute__((ext_vector_type(2)));

// Schraudolph magic: z = t + C rounds t to nearest int n (RTNE); low bits of
// z's int repr hold n+127, so bitcast(z_bits << 23) == 2^n. Valid |t| <= 126;
// here |t| <= 62 via the +-4.5 input clamp.
#define MAGIC_C 12583039.0f   // 1.5*2^23 + 127
#define RCP_MAGIC 0x7EF311C7u

// Taylor/minimax deg-4 for 2^f on [-0.5, 0.5], rel err ~4.2e-5
#define EC1 0.6931471805599453f
#define EC2 0.2402265069591007f
#define EC3 0.0555041086648216f
#define EC4 0.0096181291076285f

__device__ __forceinline__ f2 fma2(f2 a, f2 b, f2 c) {
    return __builtin_elementwise_fma(a, b, c);
}

// Two synapses (adjacent j rows), fully packed, no transcendentals:
//   t = a*v + b ; 2^t via magic-round + deg-4 poly ; A = 1 + 2^t
//   r = 1/A via bit-trick + 2 Newton ; red += w*r ; num += we*r
__device__ __forceinline__ void syn2(const f2 a, const f2 b, const f2 w,
                                     const f2 we, const f2 v2,
                                     f2& red, f2& num) {
    const f2 one = {1.0f, 1.0f};
    const f2 C2 = {MAGIC_C, MAGIC_C};
    f2 t = fma2(a, v2, b);
    f2 z = t + C2;                       // n = round(t) encoded in mantissa
    f2 n = z - C2;                       // n as float (exact)
    f2 f = t - n;                        // f in [-0.5, 0.5] (exact)
    f2 p = fma2(f2{EC4, EC4}, f, f2{EC3, EC3});
    p = fma2(p, f, f2{EC2, EC2});
    p = fma2(p, f, f2{EC1, EC1});
    p = fma2(p, f, one);                 // p = 2^f
    u2 zi = __builtin_bit_cast(u2, z);
    f2 s = __builtin_bit_cast(f2, zi << 23);   // s = 2^n
    f2 A = fma2(p, s, one);              // A = 1 + 2^t
    // packed reciprocal: bit-trick init + 2 Newton iterations
    u2 magic = {RCP_MAGIC, RCP_MAGIC};
    f2 r = __builtin_bit_cast(f2, magic - __builtin_bit_cast(u2, A));
    f2 e = fma2(-A, r, one);
    r = fma2(r, e, r);
    e = fma2(-A, r, one);
    r = fma2(r, e, r);                   // r = 1/A = sigmoid
    red = fma2(w, r, red);
    num = fma2(we, r, num);
}

// Pair-packed params: for row-pair p (rows 2p,2p+1), col u:
//   outA[p*cols+u] = {-A0, -A1, A0*mu0, A1*mu1}   (A = sigma*log2e)
//   outB[p*cols+u] = {W0, W1, W0*erev0, W1*erev1}
__global__ void prep_pair_kernel(const float* __restrict__ mu,
                                 const float* __restrict__ sigma,
                                 const float* __restrict__ W,
                                 const float* __restrict__ erev,
                                 float4* __restrict__ outA,
                                 float4* __restrict__ outB, int n) {
    int i = blockIdx.x * blockDim.x + threadIdx.x;  // i = p*UNITS + u
    if (i < n) {
        int p = i >> 8;
        int u = i & (UNITS - 1);
        int i0 = (2 * p) * UNITS + u;
        int i1 = i0 + UNITS;
        float A0 = sigma[i0] * LOG2E, A1 = sigma[i1] * LOG2E;
        outA[i] = make_float4(-A0, -A1, A0 * mu[i0], A1 * mu[i1]);
        float w0 = W[i0], w1 = W[i1];
        outB[i] = make_float4(w0, w1, w0 * erev[i0], w1 * erev[i1]);
    }
}

#define LO(q) __builtin_shufflevector(q, q, 0, 1)
#define HI(q) __builtin_shufflevector(q, q, 2, 3)

// Block: 512 threads = (u: 0..255) x (h: reduction half 0..1). RB=4 rows.
__global__ __launch_bounds__(512, 4) void ltc_kernel(
    const f4* __restrict__ rpA,   // [UNITS/2][UNITS] recurrent pair params
    const f4* __restrict__ rpB,
    const f4* __restrict__ spA,   // [IN_DIM/2][UNITS] sensory pair params
    const f4* __restrict__ spB,
    const float* __restrict__ inputs, // [BATCH][IN_DIM]
    const float* __restrict__ state,  // [BATCH][UNITS]
    const float* __restrict__ vleak,
    const float* __restrict__ gleak,
    const float* __restrict__ cm_t,
    float* __restrict__ out)          // [BATCH][UNITS]
{
    const int tid = threadIdx.x;
    const int u = tid & (UNITS - 1);
    const int h = tid >> 8;
    const int b0 = blockIdx.x * RB;

    __shared__ __align__(16) float v_sh[RB][UNITS];
    __shared__ __align__(16) float in_sh[RB][IN_DIM];
    __shared__ float nb_sh[RB][UNITS];   // glvl + snum
    __shared__ float db_sh[RB][UNITS];   // cm + gl + sden + EPS
    __shared__ float cm_sh[UNITS];
    __shared__ float pred[2][RB][UNITS];
    __shared__ float pnum[2][RB][UNITS];

    // ---- stage rows. v_sh holds CLAMPED v (synapse input only; |t|<=62).
    //      Unclamped v kept in registers for the cm*v term. ----
    if (h == 0) {
        #pragma unroll
        for (int rb = 0; rb < RB; ++rb) {
            float s = state[(b0 + rb) * UNITS + u];
            v_sh[rb][u] = fminf(fmaxf(s, -VCLAMP), VCLAMP);
        }
        cm_sh[u] = cm_t[u];
    } else {
        #pragma unroll
        for (int k = u; k < RB * IN_DIM; k += UNITS) {
            int rb = k >> 7;
            int i  = k & (IN_DIM - 1);
            float x = inputs[(b0 + rb) * IN_DIM + i];
            in_sh[rb][i] = fminf(fmaxf(x, -VCLAMP), VCLAMP);
        }
    }
    float vfull[2];
    #pragma unroll
    for (int k = 0; k < 2; ++k)
        vfull[k] = state[(b0 + h + 2 * k) * UNITS + u];
    __syncthreads();

    // ---- sensory path: half h sums i in [h*64, h*64+64) = 32 pairs ----
    {
        f2 sden[RB] = {{0.f,0.f},{0.f,0.f},{0.f,0.f},{0.f,0.f}};
        f2 snum[RB] = {{0.f,0.f},{0.f,0.f},{0.f,0.f},{0.f,0.f}};
        const int ibase = h * (IN_DIM / 2);
        for (int ic = 0; ic < IN_DIM / 2; ic += 4) {
            const int i = ibase + ic;
            const int pr = i >> 1;
            f4 qa0 = spA[(pr + 0) * UNITS + u];
            f4 qb0 = spB[(pr + 0) * UNITS + u];
            f4 qa1 = spA[(pr + 1) * UNITS + u];
            f4 qb1 = spB[(pr + 1) * UNITS + u];
            #pragma unroll
            for (int rb = 0; rb < RB; ++rb) {
                f4 x4 = *reinterpret_cast<const f4*>(&in_sh[rb][i]);
                syn2(LO(qa0), HI(qa0), LO(qb0), HI(qb0), LO(x4), sden[rb], snum[rb]);
                syn2(LO(qa1), HI(qa1), LO(qb1), HI(qb1), HI(x4), sden[rb], snum[rb]);
            }
        }
        #pragma unroll
        for (int rb = 0; rb < RB; ++rb) {
            pred[h][rb][u] = sden[rb].x + sden[rb].y;
            pnum[h][rb][u] = snum[rb].x + snum[rb].y;
        }
    }
    __syncthreads();

    // combine sensory partials into per-(rb,u) bases
    #pragma unroll
    for (int k = 0; k < 2; ++k) {
        const int rb = h + 2 * k;
        float gl = gleak[u];
        float sd = pred[0][rb][u] + pred[1][rb][u];
        float sn = pnum[0][rb][u] + pnum[1][rb][u];
        db_sh[rb][u] = cm_sh[u] + gl + sd + EPS;
        nb_sh[rb][u] = fmaf(gl, vleak[u], sn);
    }
    __syncthreads();

    // ---- 12 folds: half h reduces j in [h*128, h*128+128) = 64 pairs ----
    for (int f = 0; f < NFOLDS; ++f) {
        f2 wred[RB] = {{0.f,0.f},{0.f,0.f},{0.f,0.f},{0.f,0.f}};
        f2 wnum[RB] = {{0.f,0.f},{0.f,0.f},{0.f,0.f},{0.f,0.f}};
        const int jbase = h * (UNITS / 2);
        for (int jc = 0; jc < UNITS / 2; jc += 4) {
            const int j = jbase + jc;
            const int pr = j >> 1;
            f4 qa0 = rpA[(pr + 0) * UNITS + u];
            f4 qb0 = rpB[(pr + 0) * UNITS + u];
            f4 qa1 = rpA[(pr + 1) * UNITS + u];
            f4 qb1 = rpB[(pr + 1) * UNITS + u];
            #pragma unroll
            for (int rb = 0; rb < RB; ++rb) {
                f4 v4 = *reinterpret_cast<const f4*>(&v_sh[rb][j]);
                syn2(LO(qa0), HI(qa0), LO(qb0), HI(qb0), LO(v4), wred[rb], wnum[rb]);
                syn2(LO(qa1), HI(qa1), LO(qb1), HI(qb1), HI(v4), wred[rb], wnum[rb]);
            }
        }
        #pragma unroll
        for (int rb = 0; rb < RB; ++rb) {
            pred[h][rb][u] = wred[rb].x + wred[rb].y;
            pnum[h][rb][u] = wnum[rb].x + wnum[rb].y;
        }
        __syncthreads();

        #pragma unroll
        for (int k = 0; k < 2; ++k) {
            const int rb = h + 2 * k;
            float wr = pred[0][rb][u] + pred[1][rb][u];
            float wn = pnum[0][rb][u] + pnum[1][rb][u];
            float num = fmaf(cm_sh[u], vfull[k], nb_sh[rb][u]) + wn;
            float den = db_sh[rb][u] + wr;
            float vn = num * RCPF(den);
            vfull[k] = vn;                                   // exact v for cm*v
            v_sh[rb][u] = fminf(fmaxf(vn, -VCLAMP), VCLAMP); // synapse input
            if (f == NFOLDS - 1)
                out[(b0 + rb) * UNITS + u] = vn;
        }
        __syncthreads();
    }
}

extern "C" void kernel_launch(void* const* d_in, const int* in_sizes, int n_in,
                              void* d_out, int out_size, void* d_ws, size_t ws_size,
                              hipStream_t stream) {
    const float* inputs       = (const float*)d_in[0];
    const float* state        = (const float*)d_in[1];
    const float* sensory_mu   = (const float*)d_in[2];
    const float* sensory_sig  = (const float*)d_in[3];
    const float* sensory_W    = (const float*)d_in[4];
    const float* sensory_erev = (const float*)d_in[5];
    const float* mu           = (const float*)d_in[6];
    const float* sigma        = (const float*)d_in[7];
    const float* W            = (const float*)d_in[8];
    const float* erev         = (const float*)d_in[9];
    const float* vleak        = (const float*)d_in[10];
    const float* gleak        = (const float*)d_in[11];
    const float* cm_t         = (const float*)d_in[12];
    float* out = (float*)d_out;

    float4* rpA = (float4*)d_ws;
    float4* rpB = rpA + (UNITS / 2) * UNITS;
    float4* spA = rpB + (UNITS / 2) * UNITS;
    float4* spB = spA + (IN_DIM / 2) * UNITS;

    int n_rec = (UNITS / 2) * UNITS;   // 32768 pair-slots
    int n_sen = (IN_DIM / 2) * UNITS;  // 16384
    prep_pair_kernel<<<(n_rec + 255) / 256, 256, 0, stream>>>(
        mu, sigma, W, erev, rpA, rpB, n_rec);
    prep_pair_kernel<<<(n_sen + 255) / 256, 256, 0, stream>>>(
        sensory_mu, sensory_sig, sensory_W, sensory_erev, spA, spB, n_sen);

    ltc_kernel<<<BATCH / RB, 512, 0, stream>>>(
        (const f4*)rpA, (const f4*)rpB, (const f4*)spA, (const f4*)spB,
        inputs, state, vleak, gleak, cm_t, out);
}